// Round 3
// baseline (1940.122 us; speedup 1.0000x reference)
//
#include <hip/hip_runtime.h>

// Problem constants
constexpr int TT = 512;    // sequence length
constexpr int BB = 2048;   // batch
constexpr int HH = 11;     // hidden size
constexpr int GG = 44;     // 4*HH gates
constexpr int NL = 5;      // layers

typedef float v2f __attribute__((ext_vector_type(2)));

__device__ __forceinline__ float readlane_f(float v, int l) {
    return __int_as_float(__builtin_amdgcn_readlane(__float_as_int(v), l));
}
// quad_perm broadcast of lane q within each quad (ctrl = q * 0x55)
__device__ __forceinline__ float dpp_q0(float v) {
    return __int_as_float(__builtin_amdgcn_mov_dpp(__float_as_int(v), 0x00, 0xF, 0xF, false));
}
__device__ __forceinline__ float dpp_q1(float v) {
    return __int_as_float(__builtin_amdgcn_mov_dpp(__float_as_int(v), 0x55, 0xF, 0xF, false));
}
__device__ __forceinline__ float dpp_q2(float v) {
    return __int_as_float(__builtin_amdgcn_mov_dpp(__float_as_int(v), 0xAA, 0xF, 0xF, false));
}
__device__ __forceinline__ float dpp_q3(float v) {
    return __int_as_float(__builtin_amdgcn_mov_dpp(__float_as_int(v), 0xFF, 0xF, 0xF, false));
}

// inp[b][t] = sum_k x[b][0][k][t]
__global__ void reduce_x(const float* __restrict__ x, float* __restrict__ inp) {
    int t = blockIdx.x * 256 + threadIdx.x;   // grid.x = 2 -> t in [0,512)
    int b = blockIdx.y;
    const float* p = x + (size_t)b * 32 * TT + t;
    float s = 0.f;
#pragma unroll
    for (int k = 0; k < 32; k++) s += p[k * TT];
    inp[(size_t)b * TT + t] = s;
}

// One wave per (batch, dir). Lane = 4*u + q, u = hidden unit, q = gate
// (0:i 1:f 2:g 3:o). Weight row in W is q*HH + u. Lanes with u >= 11 run
// with zero weights (benign), stores masked.
//
// Scaled domain: weights/bias pre-multiplied by -log2e (gates i,f,o) or
// -2*log2e (gate g). The g activation additionally carries the -2*log2e
// factor (ascale/aoff), so c is kept as c' = -2*log2e*c_true and
// exp2(c') = exp(-2c) feeds the output tanh with no per-step multiply.
template <int IND>
__global__ __launch_bounds__(256, 4)   // 4 waves/EU min -> 128-VGPR budget
void lstm_layer(
    const float* __restrict__ xin,   // [chunk][TT][IND]
    float* __restrict__ out,         // [chunk][TT][22]
    const float* __restrict__ Wih,   // [2][GG][IND]
    const float* __restrict__ Whh,   // [2][GG][HH]
    const float* __restrict__ bih,   // [2][GG]
    const float* __restrict__ bhh)   // [2][GG]
{
    constexpr int NP = (IND > 1) ? IND / 2 : 1;   // v2f pairs per x row

    const float L2E   = 1.4426950408889634f;
    const float NL2E  = -L2E;
    const float N2L2E = -2.f * L2E;

    int tid  = threadIdx.x;
    int lane = tid & 63;
    int u = lane >> 2;
    int q = lane & 3;
    bool active = (u < HH);
    int grow = q * HH + u;

    // uniform (scalar) sequence id: weights, bias, output base
    int seq_u = __builtin_amdgcn_readfirstlane((int)blockIdx.x * 4 + (tid >> 6));
    int b_u = seq_u >> 1;
    int d_u = seq_u & 1;

    // divergent-looking copy for x addressing: compiler cannot prove
    // tid>>6 uniform, so x loads stay VMEM (in-order vmcnt waits) instead
    // of scalarizing to SMEM s_load (OOO -> lgkmcnt(0) drains kill the
    // prefetch).
    int seq_v = (int)blockIdx.x * 4 + (tid >> 6);
    int b_v = seq_v >> 1;
    int d_v = seq_v & 1;

    float esc    = (q == 2) ? N2L2E : NL2E;
    float ascale = (q == 2) ? 2.f * N2L2E : 1.f;
    float aoff   = (q == 2) ? -N2L2E : 0.f;

    v2f   wih2[NP];
    float wih0 = 0.f;
    float whh[HH];
    float biasv = 0.f;
    if (active) {
        const float* wi = Wih + (size_t)(d_u * GG + grow) * IND;
        if constexpr (IND == 1) {
            wih0 = wi[0] * esc;
        } else {
#pragma unroll
            for (int p = 0; p < NP; p++) wih2[p] = ((const v2f*)wi)[p] * esc;
        }
        const float* wh = Whh + (size_t)(d_u * GG + grow) * HH;
#pragma unroll
        for (int j = 0; j < HH; j++) whh[j] = wh[j] * esc;
        biasv = (bih[d_u * GG + grow] + bhh[d_u * GG + grow]) * esc;
    } else {
        if constexpr (IND != 1) {
#pragma unroll
            for (int p = 0; p < NP; p++) wih2[p] = (v2f){0.f, 0.f};
        }
#pragma unroll
        for (int j = 0; j < HH; j++) whh[j] = 0.f;
    }

    float hs[HH];   // broadcast via readlane -> SGPR-resident
#pragma unroll
    for (int j = 0; j < HH; j++) hs[j] = 0.f;
    float c = 0.f;   // scaled domain c' = -2*log2e * c_true

    const int dstep = d_v ? -IND : IND;              // x row stride (floats)
    const float* xrow = xin + (size_t)b_v * TT * IND + (size_t)(d_v ? (TT - 1) * IND : 0);

    const int ostep = d_u ? -22 : 22;                // out row stride (floats)
    float* orow = out + (size_t)b_u * TT * 22 + (size_t)(d_u ? (TT - 1) * 22 : 0);
    const int olane = d_u * HH + u;
    const bool doStore = (q == 0) && active;

    // depth-2 register ping-pong; refill consumed buffer with row S+2
    v2f   X0[NP], X1[NP];
    float X0s = 0.f, X1s = 0.f;
    if constexpr (IND == 1) {
        X0s = xrow[0];
        X1s = xrow[dstep];
    } else {
#pragma unroll
        for (int p = 0; p < NP; p++) X0[p] = ((const v2f*)xrow)[p];
#pragma unroll
        for (int p = 0; p < NP; p++) X1[p] = ((const v2f*)(xrow + dstep))[p];
    }
    xrow += dstep;   // points at last-loaded row (t-index 1)

#define LSTM_STEP(XB, XBs, REFILL)                                            \
    do {                                                                      \
        float pre;                                                            \
        if constexpr (IND == 1) {                                             \
            pre = XBs * wih0;                                                 \
        } else {                                                              \
            v2f va = XB[0] * wih2[0];                                         \
            v2f vb = XB[1] * wih2[1];                                         \
            _Pragma("unroll")                                                 \
            for (int p = 2; p < NP; p++) {                                    \
                if (p & 1) vb = __builtin_elementwise_fma(XB[p], wih2[p], vb);\
                else       va = __builtin_elementwise_fma(XB[p], wih2[p], va);\
            }                                                                 \
            va = va + vb;                                                     \
            pre = va.x + va.y;                                                \
        }                                                                     \
        if (REFILL) {  /* compile-time flag: reload this buffer with S+2 */   \
            xrow += dstep;                                                    \
            if constexpr (IND == 1) {                                         \
                XBs = xrow[0];                                                \
            } else {                                                          \
                _Pragma("unroll")                                             \
                for (int p = 0; p < NP; p++) XB[p] = ((const v2f*)xrow)[p];   \
            }                                                                 \
        }                                                                     \
        float ha = fmaf(hs[0], whh[0], biasv);                                \
        float hb = hs[1] * whh[1];                                            \
        _Pragma("unroll")                                                     \
        for (int j = 2; j < HH; j++) {                                        \
            if (j & 1) hb = fmaf(hs[j], whh[j], hb);                          \
            else       ha = fmaf(hs[j], whh[j], ha);                          \
        }                                                                     \
        pre = pre + ha + hb;                                                  \
        float e   = __builtin_amdgcn_exp2f(pre);                              \
        float act = fmaf(ascale, __builtin_amdgcn_rcpf(1.f + e), aoff);       \
        float iv = dpp_q0(act);                                               \
        float fv = dpp_q1(act);                                               \
        float gv = dpp_q2(act);                                               \
        float ov = dpp_q3(act);                                               \
        c = fmaf(fv, c, iv * gv);                                             \
        float e2 = __builtin_amdgcn_exp2f(c);                                 \
        float th = fmaf(2.f, __builtin_amdgcn_rcpf(1.f + e2), -1.f);          \
        float h  = ov * th;                                                   \
        if (doStore) orow[olane] = h;                                         \
        orow += ostep;                                                        \
        _Pragma("unroll")                                                     \
        for (int j = 0; j < HH; j++) hs[j] = readlane_f(h, 4 * j);            \
    } while (0)

    // main loop: steps 0..TT-3 with unconditional refill of row S+2
    for (int s = 0; s < TT - 2; s += 2) {
        LSTM_STEP(X0, X0s, true);
        LSTM_STEP(X1, X1s, true);
    }
    // tail: steps TT-2, TT-1 consume the final two buffered rows
    LSTM_STEP(X0, X0s, false);
    LSTM_STEP(X1, X1s, false);
#undef LSTM_STEP
}

extern "C" void kernel_launch(void* const* d_in, const int* in_sizes, int n_in,
                              void* d_out, int out_size, void* d_ws, size_t ws_size,
                              hipStream_t stream) {
    const float* x        = (const float*)d_in[0]; // [2048,1,32,512]
    const float* W_ih0    = (const float*)d_in[1]; // [2,44,1]
    const float* W_ih_rest= (const float*)d_in[2]; // [4,2,44,22]
    const float* W_hh     = (const float*)d_in[3]; // [5,2,44,11]
    const float* b_ih     = (const float*)d_in[4]; // [5,2,44]
    const float* b_hh     = (const float*)d_in[5]; // [5,2,44]
    float* out = (float*)d_out;                    // [2048,512,22]

    // Workspace: one ping buffer of chunk*TT*22 floats; largest pow2 chunk
    // that fits ws_size. The x-reduction is staged in the same buffer (its
    // lifetime ends when layer 1 overwrites it). d_out is the pong buffer.
    const size_t perB = (size_t)TT * 22 * sizeof(float);
    int chunk = BB;
    while (chunk > 2 && (size_t)chunk * perB > ws_size) chunk >>= 1;
    float* wsbuf = (float*)d_ws;

    for (int c0 = 0; c0 < BB; c0 += chunk) {
        const float* xc   = x + (size_t)c0 * 32 * TT;
        float*       outc = out + (size_t)c0 * TT * 22;
        const int nblk = (chunk * 2) / 4;  // 4 sequences (waves) per block

        reduce_x<<<dim3(2, chunk), 256, 0, stream>>>(xc, wsbuf);

        lstm_layer<1><<<nblk, 256, 0, stream>>>(wsbuf, outc, W_ih0, W_hh, b_ih, b_hh);

        for (int l = 1; l < NL; l++) {
            const float* src = (l & 1) ? outc : wsbuf;
            float*       dst = (l & 1) ? wsbuf : outc;
            lstm_layer<22><<<nblk, 256, 0, stream>>>(
                src, dst,
                W_ih_rest + (size_t)(l - 1) * 2 * GG * 22,
                W_hh + (size_t)l * 2 * GG * HH,
                b_ih + (size_t)l * 2 * GG,
                b_hh + (size_t)l * 2 * GG);
        }
    }
}

// Round 4
// 1296.241 us; speedup vs baseline: 1.4967x; 1.4967x over previous
//
#include <hip/hip_runtime.h>

// Problem constants
constexpr int TT = 512;    // sequence length
constexpr int BB = 2048;   // batch
constexpr int HH = 11;     // hidden size
constexpr int GG = 44;     // 4*HH gates
constexpr int NL = 5;      // layers

typedef float v2f __attribute__((ext_vector_type(2)));

__device__ __forceinline__ float readlane_f(float v, int l) {
    return __int_as_float(__builtin_amdgcn_readlane(__float_as_int(v), l));
}
// quad_perm broadcast of lane q within each quad (ctrl = q * 0x55)
__device__ __forceinline__ float dpp_q0(float v) {
    return __int_as_float(__builtin_amdgcn_mov_dpp(__float_as_int(v), 0x00, 0xF, 0xF, false));
}
__device__ __forceinline__ float dpp_q1(float v) {
    return __int_as_float(__builtin_amdgcn_mov_dpp(__float_as_int(v), 0x55, 0xF, 0xF, false));
}
__device__ __forceinline__ float dpp_q2(float v) {
    return __int_as_float(__builtin_amdgcn_mov_dpp(__float_as_int(v), 0xAA, 0xF, 0xF, false));
}
__device__ __forceinline__ float dpp_q3(float v) {
    return __int_as_float(__builtin_amdgcn_mov_dpp(__float_as_int(v), 0xFF, 0xF, 0xF, false));
}

// inp[b][t] = sum_k x[b][0][k][t]
__global__ void reduce_x(const float* __restrict__ x, float* __restrict__ inp) {
    int t = blockIdx.x * 256 + threadIdx.x;   // grid.x = 2 -> t in [0,512)
    int b = blockIdx.y;
    const float* p = x + (size_t)b * 32 * TT + t;
    float s = 0.f;
#pragma unroll
    for (int k = 0; k < 32; k++) s += p[k * TT];
    inp[(size_t)b * TT + t] = s;
}

// One wave per (batch, dir). Lane = 4*u + q, u = hidden unit, q = gate
// (0:i 1:f 2:g 3:o). Weight row in W is q*HH + u. Lanes u >= 11 run with
// zero weights (benign), stores masked.
//
// x staging: per-wave-private LDS chunks (CH rows), double-buffered.
// Chunk c+1 is loaded into registers (NLD dwords/lane) at the START of
// chunk c's 32 steps (vmcnt-covered by the whole chunk), ds_written at the
// end. Rows are read per step via broadcast ds_read (ping-ponged one row
// ahead). No barriers: LDS regions are wave-private.
//
// Scaled domain: weights/bias pre-multiplied by -log2e (i,f,o) or
// -2*log2e (g); c kept as c' = -2*log2e*c_true so both exp2 inputs need
// no per-step multiply.
template <int IND>
__global__ __launch_bounds__(256, 4)   // 4 waves/EU -> 128-VGPR budget
void lstm_layer(
    const float* __restrict__ xin,   // [chunk][TT][IND]
    float* __restrict__ out,         // [chunk][TT][22]
    const float* __restrict__ Wih,   // [2][GG][IND]
    const float* __restrict__ Whh,   // [2][GG][HH]
    const float* __restrict__ bih,   // [2][GG]
    const float* __restrict__ bhh)   // [2][GG]
{
    constexpr int NP  = (IND > 1) ? IND / 2 : 1;  // v2f pairs per x row
    constexpr int CH  = (IND == 1) ? 64 : 32;     // rows per staged chunk
    constexpr int NCH = TT / CH;                  // chunks per sequence
    constexpr int NLD = (CH * IND) / 64;          // dwords per lane per chunk

    __shared__ float smem[4 * 2 * CH * IND];      // [wave][buf][CH*IND]

    const float L2E   = 1.4426950408889634f;
    const float NL2E  = -L2E;
    const float N2L2E = -2.f * L2E;

    int tid  = threadIdx.x;
    int lane = tid & 63;
    int wid  = tid >> 6;
    int u = lane >> 2;
    int q = lane & 3;
    bool active = (u < HH);
    int grow = q * HH + u;

    int seq = __builtin_amdgcn_readfirstlane((int)blockIdx.x * 4 + wid);
    int b = seq >> 1;
    int d = seq & 1;

    float esc    = (q == 2) ? N2L2E : NL2E;
    float ascale = (q == 2) ? 2.f * N2L2E : 1.f;
    float aoff   = (q == 2) ? -N2L2E : 0.f;

    v2f   wih2[NP];
    float wih0 = 0.f;
    float whh[HH];
    float biasv = 0.f;
    if (active) {
        const float* wi = Wih + (size_t)(d * GG + grow) * IND;
        if constexpr (IND == 1) {
            wih0 = wi[0] * esc;
        } else {
#pragma unroll
            for (int p = 0; p < NP; p++) wih2[p] = ((const v2f*)wi)[p] * esc;
        }
        const float* wh = Whh + (size_t)(d * GG + grow) * HH;
#pragma unroll
        for (int j = 0; j < HH; j++) whh[j] = wh[j] * esc;
        biasv = (bih[d * GG + grow] + bhh[d * GG + grow]) * esc;
    } else {
        if constexpr (IND != 1) {
#pragma unroll
            for (int p = 0; p < NP; p++) wih2[p] = (v2f){0.f, 0.f};
        }
#pragma unroll
        for (int j = 0; j < HH; j++) whh[j] = 0.f;
    }

    float hs[HH];   // broadcast via readlane -> SGPR-resident
#pragma unroll
    for (int j = 0; j < HH; j++) hs[j] = 0.f;
    float c = 0.f;  // scaled domain c' = -2*log2e * c_true

    const int ostep = d ? -22 : 22;
    float* orow = out + (size_t)b * TT * 22 + (size_t)(d ? (TT - 1) * 22 : 0);
    const int olane = d * HH + u;
    const bool doStore = (q == 0) && active;

    // ---- x chunk staging setup ----
    float* sw = smem + wid * (2 * CH * IND);            // this wave's region
    const float* gbase = xin + (size_t)b * TT * IND
                             + (size_t)(d ? (TT - CH) * IND : 0);
    const int gstep = d ? -(CH * IND) : (CH * IND);     // chunk-to-chunk
    const int lstep = d ? -IND : IND;                   // row-to-row in LDS

    {   // stage chunk 0 (regs -> LDS)
        float p0[NLD];
#pragma unroll
        for (int k = 0; k < NLD; k++) p0[k] = gbase[k * 64 + lane];
#pragma unroll
        for (int k = 0; k < NLD; k++) sw[k * 64 + lane] = p0[k];
    }
    int buf = 0;
    float* swc = sw;
    const float* lrow = swc + (d ? (CH - 1) * IND : 0); // first consumed row

    // row register ping-pong (one row of lookahead over LDS)
    v2f   xA[NP], xB[NP];
    float xAs = 0.f, xBs = 0.f;
    if constexpr (IND == 1) {
        xAs = lrow[0];
    } else {
#pragma unroll
        for (int p = 0; p < NP; p++) xA[p] = ((const v2f*)lrow)[p];
    }

    const float* gnext = gbase + gstep;                 // chunk 1 source

#define LSTM_STEP(XC, XN, DOPF)                                               \
    do {                                                                      \
        float pre;                                                            \
        if constexpr (IND == 1) {                                             \
            pre = XC##s * wih0;                                               \
        } else {                                                              \
            v2f va = XC[0] * wih2[0];                                         \
            v2f vb = XC[1] * wih2[1];                                         \
            _Pragma("unroll")                                                 \
            for (int p = 2; p < NP; p++) {                                    \
                if (p & 1) vb = __builtin_elementwise_fma(XC[p], wih2[p], vb);\
                else       va = __builtin_elementwise_fma(XC[p], wih2[p], va);\
            }                                                                 \
            va = va + vb;                                                     \
            pre = va.x + va.y;                                                \
        }                                                                     \
        if (DOPF) {  /* prefetch next consumed row from LDS */                \
            lrow += lstep;                                                    \
            if constexpr (IND == 1) {                                         \
                XN##s = lrow[0];                                              \
            } else {                                                          \
                _Pragma("unroll")                                             \
                for (int p = 0; p < NP; p++) XN[p] = ((const v2f*)lrow)[p];   \
            }                                                                 \
        }                                                                     \
        float ha = fmaf(hs[0], whh[0], biasv);                                \
        float hb = hs[1] * whh[1];                                            \
        _Pragma("unroll")                                                     \
        for (int j = 2; j < HH; j++) {                                        \
            if (j & 1) hb = fmaf(hs[j], whh[j], hb);                          \
            else       ha = fmaf(hs[j], whh[j], ha);                          \
        }                                                                     \
        pre = pre + ha + hb;                                                  \
        float e   = __builtin_amdgcn_exp2f(pre);                              \
        float act = fmaf(ascale, __builtin_amdgcn_rcpf(1.f + e), aoff);       \
        float iv = dpp_q0(act);                                               \
        float fv = dpp_q1(act);                                               \
        float gv = dpp_q2(act);                                               \
        float ov = dpp_q3(act);                                               \
        c = fmaf(fv, c, iv * gv);                                             \
        float e2 = __builtin_amdgcn_exp2f(c);                                 \
        float th = fmaf(2.f, __builtin_amdgcn_rcpf(1.f + e2), -1.f);          \
        float h  = ov * th;                                                   \
        if (doStore) orow[olane] = h;                                         \
        orow += ostep;                                                        \
        _Pragma("unroll")                                                     \
        for (int j = 0; j < HH; j++) hs[j] = readlane_f(h, 4 * j);            \
    } while (0)

    for (int ch = 0; ch < NCH; ch++) {
        const bool last = (ch + 1 == NCH);
        float pf[NLD];
        if (!last) {   // issue next-chunk loads now; vmcnt-covered by CH steps
#pragma unroll
            for (int k = 0; k < NLD; k++) pf[k] = gnext[k * 64 + lane];
        }
        // steps 0 .. CH-3 (pairs), each prefetches its successor row
        for (int sl = 0; sl < CH - 2; sl += 2) {
            LSTM_STEP(xA, xB, true);
            LSTM_STEP(xB, xA, true);
        }
        LSTM_STEP(xA, xB, true);     // step CH-2 (prefetches row CH-1)
        LSTM_STEP(xB, xA, false);    // step CH-1 (no in-chunk prefetch)
        if (!last) {
            float* swn = sw + ((buf ^ 1) ? CH * IND : 0);
#pragma unroll
            for (int k = 0; k < NLD; k++) swn[k * 64 + lane] = pf[k];
            buf ^= 1;
            swc = swn;
            lrow = swc + (d ? (CH - 1) * IND : 0);
            if constexpr (IND == 1) {
                xAs = lrow[0];
            } else {
#pragma unroll
                for (int p = 0; p < NP; p++) xA[p] = ((const v2f*)lrow)[p];
            }
            gnext += gstep;
        }
    }
#undef LSTM_STEP
}

extern "C" void kernel_launch(void* const* d_in, const int* in_sizes, int n_in,
                              void* d_out, int out_size, void* d_ws, size_t ws_size,
                              hipStream_t stream) {
    const float* x        = (const float*)d_in[0]; // [2048,1,32,512]
    const float* W_ih0    = (const float*)d_in[1]; // [2,44,1]
    const float* W_ih_rest= (const float*)d_in[2]; // [4,2,44,22]
    const float* W_hh     = (const float*)d_in[3]; // [5,2,44,11]
    const float* b_ih     = (const float*)d_in[4]; // [5,2,44]
    const float* b_hh     = (const float*)d_in[5]; // [5,2,44]
    float* out = (float*)d_out;                    // [2048,512,22]

    // Workspace: one ping buffer of chunk*TT*22 floats; largest pow2 chunk
    // that fits ws_size. The x-reduction is staged in the same buffer (its
    // lifetime ends when layer 1 overwrites it). d_out is the pong buffer.
    const size_t perB = (size_t)TT * 22 * sizeof(float);
    int chunk = BB;
    while (chunk > 2 && (size_t)chunk * perB > ws_size) chunk >>= 1;
    float* wsbuf = (float*)d_ws;

    for (int c0 = 0; c0 < BB; c0 += chunk) {
        const float* xc   = x + (size_t)c0 * 32 * TT;
        float*       outc = out + (size_t)c0 * TT * 22;
        const int nblk = (chunk * 2) / 4;  // 4 sequences (waves) per block

        reduce_x<<<dim3(2, chunk), 256, 0, stream>>>(xc, wsbuf);

        lstm_layer<1><<<nblk, 256, 0, stream>>>(wsbuf, outc, W_ih0, W_hh, b_ih, b_hh);

        for (int l = 1; l < NL; l++) {
            const float* src = (l & 1) ? outc : wsbuf;
            float*       dst = (l & 1) ? wsbuf : outc;
            lstm_layer<22><<<nblk, 256, 0, stream>>>(
                src, dst,
                W_ih_rest + (size_t)(l - 1) * 2 * GG * 22,
                W_hh + (size_t)l * 2 * GG * HH,
                b_ih + (size_t)l * 2 * GG,
                b_hh + (size_t)l * 2 * GG);
        }
    }
}

// Round 5
// 1206.529 us; speedup vs baseline: 1.6080x; 1.0744x over previous
//
#include <hip/hip_runtime.h>

// Problem constants
constexpr int TT = 512;    // sequence length
constexpr int BB = 2048;   // batch
constexpr int HH = 11;     // hidden size
constexpr int GG = 44;     // 4*HH gates
constexpr int NL = 5;      // layers

typedef float v2f __attribute__((ext_vector_type(2)));

__device__ __forceinline__ float readlane_f(float v, int l) {
    return __int_as_float(__builtin_amdgcn_readlane(__float_as_int(v), l));
}
// quad_perm broadcast of lane q within each quad (ctrl = q * 0x55)
__device__ __forceinline__ float dpp_q0(float v) {
    return __int_as_float(__builtin_amdgcn_mov_dpp(__float_as_int(v), 0x00, 0xF, 0xF, false));
}
__device__ __forceinline__ float dpp_q1(float v) {
    return __int_as_float(__builtin_amdgcn_mov_dpp(__float_as_int(v), 0x55, 0xF, 0xF, false));
}
__device__ __forceinline__ float dpp_q3(float v) {
    return __int_as_float(__builtin_amdgcn_mov_dpp(__float_as_int(v), 0xFF, 0xF, 0xF, false));
}
// quad_perm [2,3,0,1]: lane q gets lane q^2 of its quad (ctrl 0x4E)
__device__ __forceinline__ float dpp_qswap2(float v) {
    return __int_as_float(__builtin_amdgcn_mov_dpp(__float_as_int(v), 0x4E, 0xF, 0xF, false));
}

// inp[b][t] = sum_k x[b][0][k][t]
__global__ void reduce_x(const float* __restrict__ x, float* __restrict__ inp) {
    int t = blockIdx.x * 256 + threadIdx.x;   // grid.x = 2 -> t in [0,512)
    int b = blockIdx.y;
    const float* p = x + (size_t)b * 32 * TT + t;
    float s = 0.f;
#pragma unroll
    for (int k = 0; k < 32; k++) s += p[k * TT];
    inp[(size_t)b * TT + t] = s;
}

// One wave per (batch, dir). Lane = 4*u + q, u = hidden unit, q = gate
// (0:i 1:f 2:g 3:o). Weight row in W is q*HH + u. Lanes u >= 11 run with
// zero weights (benign), stores masked.
//
// x staging: per-wave-private LDS chunks (CH rows), double-buffered, no
// barriers (regions wave-private). Chunk c+1 global loads issue at the
// START of chunk c (vmcnt-covered by 32 steps), ds_written at the end.
//
// Scaled domain: weights/bias pre-multiplied by -log2e (i,f,o) or
// -2*log2e (g); c kept as c' = -2*log2e*c_true so both exp2 inputs need
// no per-step multiply.
//
// Packed math: h broadcast values are wave-uniform (readlane) -> v2f
// pairs of uniforms live in SGPR pairs; h-dot is 6 v_pk_fma_f32 with the
// SGPR pair as the single scalar operand. x-dot chains 11 more pk_fma
// into the same accumulator, seeded from bias2 = {bias, 0}.
template <int IND>
__global__ __launch_bounds__(256, 4)   // 4 waves/EU -> 128-VGPR budget
void lstm_layer(
    const float* __restrict__ xin,   // [chunk][TT][IND]
    float* __restrict__ out,         // [chunk][TT][22]
    const float* __restrict__ Wih,   // [2][GG][IND]
    const float* __restrict__ Whh,   // [2][GG][HH]
    const float* __restrict__ bih,   // [2][GG]
    const float* __restrict__ bhh)   // [2][GG]
{
    constexpr int NP  = (IND > 1) ? IND / 2 : 1;  // v2f pairs per x row
    constexpr int CH  = (IND == 1) ? 64 : 32;     // rows per staged chunk
    constexpr int NCH = TT / CH;                  // chunks per sequence
    constexpr int NLD = (CH * IND) / 64;          // dwords per lane per chunk

    __shared__ float smem[4 * 2 * CH * IND];      // [wave][buf][CH*IND]

    const float L2E   = 1.4426950408889634f;
    const float NL2E  = -L2E;
    const float N2L2E = -2.f * L2E;

    int tid  = threadIdx.x;
    int lane = tid & 63;
    int wid  = tid >> 6;
    int u = lane >> 2;
    int q = lane & 3;
    bool active = (u < HH);
    int grow = q * HH + u;

    int seq = __builtin_amdgcn_readfirstlane((int)blockIdx.x * 4 + wid);
    int b = seq >> 1;
    int d = seq & 1;

    float esc    = (q == 2) ? N2L2E : NL2E;
    float ascale = (q == 2) ? 2.f * N2L2E : 1.f;
    float aoff   = (q == 2) ? -N2L2E : 0.f;

    v2f   wih2[NP];
    float wih0 = 0.f;
    v2f   whh2[6];          // paired Whh row, last slot y-padded with 0
    v2f   bias2;
    if (active) {
        const float* wi = Wih + (size_t)(d * GG + grow) * IND;
        if constexpr (IND == 1) {
            wih0 = wi[0] * esc;
        } else {
#pragma unroll
            for (int p = 0; p < NP; p++) wih2[p] = ((const v2f*)wi)[p] * esc;
        }
        const float* wh = Whh + (size_t)(d * GG + grow) * HH;
#pragma unroll
        for (int k = 0; k < 5; k++)
            whh2[k] = (v2f){wh[2 * k] * esc, wh[2 * k + 1] * esc};
        whh2[5] = (v2f){wh[10] * esc, 0.f};
        float bv = (bih[d * GG + grow] + bhh[d * GG + grow]) * esc;
        bias2 = (v2f){bv, 0.f};
    } else {
        if constexpr (IND != 1) {
#pragma unroll
            for (int p = 0; p < NP; p++) wih2[p] = (v2f){0.f, 0.f};
        }
#pragma unroll
        for (int k = 0; k < 6; k++) whh2[k] = (v2f){0.f, 0.f};
        bias2 = (v2f){0.f, 0.f};
    }

    // h broadcast pairs: hp[k] = {h_{2k}, h_{2k+1}}, wave-uniform (SGPRs)
    v2f hp[6];
#pragma unroll
    for (int k = 0; k < 6; k++) hp[k] = (v2f){0.f, 0.f};
    float c = 0.f;  // scaled domain c' = -2*log2e * c_true

    const int ostep = d ? -22 : 22;
    float* orow = out + (size_t)b * TT * 22 + (size_t)(d ? (TT - 1) * 22 : 0);
    const int olane = d * HH + u;
    const bool doStore = (q == 0) && active;

    // ---- x chunk staging setup ----
    float* sw = smem + wid * (2 * CH * IND);            // this wave's region
    const float* gbase = xin + (size_t)b * TT * IND
                             + (size_t)(d ? (TT - CH) * IND : 0);
    const int gstep = d ? -(CH * IND) : (CH * IND);     // chunk-to-chunk
    const int lstep = d ? -IND : IND;                   // row-to-row in LDS

    {   // stage chunk 0 (regs -> LDS)
        float p0[NLD];
#pragma unroll
        for (int k = 0; k < NLD; k++) p0[k] = gbase[k * 64 + lane];
#pragma unroll
        for (int k = 0; k < NLD; k++) sw[k * 64 + lane] = p0[k];
    }
    int buf = 0;
    float* swc = sw;
    const float* lrow = swc + (d ? (CH - 1) * IND : 0); // first consumed row

    // row register ping-pong (one row of lookahead over LDS)
    v2f   xA[NP], xB[NP];
    float xAs = 0.f, xBs = 0.f;
    if constexpr (IND == 1) {
        xAs = lrow[0];
    } else {
#pragma unroll
        for (int p = 0; p < NP; p++) xA[p] = ((const v2f*)lrow)[p];
    }

    const float* gnext = gbase + gstep;                 // chunk 1 source

#define LSTM_STEP(XC, XN, DOPF)                                               \
    do {                                                                      \
        /* h-dot: 6 pk_fma, scalar (SGPR-pair) x VGPR-pair, seed bias2 */     \
        v2f acc = __builtin_elementwise_fma(hp[0], whh2[0], bias2);           \
        _Pragma("unroll")                                                     \
        for (int k = 1; k < 6; k++)                                           \
            acc = __builtin_elementwise_fma(hp[k], whh2[k], acc);             \
        float pre;                                                            \
        if constexpr (IND == 1) {                                             \
            pre = fmaf(XC##s, wih0, acc.x + acc.y);                           \
        } else {                                                              \
            _Pragma("unroll")                                                 \
            for (int p = 0; p < NP; p++)                                      \
                acc = __builtin_elementwise_fma(XC[p], wih2[p], acc);         \
            pre = acc.x + acc.y;                                              \
        }                                                                     \
        if (DOPF) {  /* prefetch next consumed row from LDS */                \
            lrow += lstep;                                                    \
            if constexpr (IND == 1) {                                         \
                XN##s = lrow[0];                                              \
            } else {                                                          \
                _Pragma("unroll")                                             \
                for (int p = 0; p < NP; p++) XN[p] = ((const v2f*)lrow)[p];   \
            }                                                                 \
        }                                                                     \
        float e   = __builtin_amdgcn_exp2f(pre);                              \
        float act = fmaf(ascale, __builtin_amdgcn_rcpf(1.f + e), aoff);       \
        /* lane q0: act(=i) * act@q2(=g); broadcast to quad from q0 */        \
        float ig  = act * dpp_qswap2(act);                                    \
        float igb = dpp_q0(ig);                                               \
        float fv  = dpp_q1(act);                                              \
        float ov  = dpp_q3(act);                                              \
        c = fmaf(fv, c, igb);                                                 \
        float e2 = __builtin_amdgcn_exp2f(c);                                 \
        float th = fmaf(2.f, __builtin_amdgcn_rcpf(1.f + e2), -1.f);          \
        float h  = ov * th;                                                   \
        if (doStore) orow[olane] = h;                                         \
        orow += ostep;                                                        \
        _Pragma("unroll")                                                     \
        for (int k = 0; k < 5; k++)                                           \
            hp[k] = (v2f){readlane_f(h, 8 * k), readlane_f(h, 8 * k + 4)};    \
        hp[5] = (v2f){readlane_f(h, 40), 0.f};                                \
    } while (0)

    for (int ch = 0; ch < NCH; ch++) {
        const bool last = (ch + 1 == NCH);
        float pf[NLD];
        if (!last) {   // issue next-chunk loads now; vmcnt-covered by CH steps
#pragma unroll
            for (int k = 0; k < NLD; k++) pf[k] = gnext[k * 64 + lane];
        }
        // steps 0 .. CH-3 (pairs), each prefetches its successor row
        for (int sl = 0; sl < CH - 2; sl += 2) {
            LSTM_STEP(xA, xB, true);
            LSTM_STEP(xB, xA, true);
        }
        LSTM_STEP(xA, xB, true);     // step CH-2 (prefetches row CH-1)
        LSTM_STEP(xB, xA, false);    // step CH-1 (no in-chunk prefetch)
        if (!last) {
            float* swn = sw + ((buf ^ 1) ? CH * IND : 0);
#pragma unroll
            for (int k = 0; k < NLD; k++) swn[k * 64 + lane] = pf[k];
            buf ^= 1;
            swc = swn;
            lrow = swc + (d ? (CH - 1) * IND : 0);
            if constexpr (IND == 1) {
                xAs = lrow[0];
            } else {
#pragma unroll
                for (int p = 0; p < NP; p++) xA[p] = ((const v2f*)lrow)[p];
            }
            gnext += gstep;
        }
    }
#undef LSTM_STEP
}

extern "C" void kernel_launch(void* const* d_in, const int* in_sizes, int n_in,
                              void* d_out, int out_size, void* d_ws, size_t ws_size,
                              hipStream_t stream) {
    const float* x        = (const float*)d_in[0]; // [2048,1,32,512]
    const float* W_ih0    = (const float*)d_in[1]; // [2,44,1]
    const float* W_ih_rest= (const float*)d_in[2]; // [4,2,44,22]
    const float* W_hh     = (const float*)d_in[3]; // [5,2,44,11]
    const float* b_ih     = (const float*)d_in[4]; // [5,2,44]
    const float* b_hh     = (const float*)d_in[5]; // [5,2,44]
    float* out = (float*)d_out;                    // [2048,512,22]

    // Workspace: one ping buffer of chunk*TT*22 floats; largest pow2 chunk
    // that fits ws_size. The x-reduction is staged in the same buffer (its
    // lifetime ends when layer 1 overwrites it). d_out is the pong buffer.
    const size_t perB = (size_t)TT * 22 * sizeof(float);
    int chunk = BB;
    while (chunk > 2 && (size_t)chunk * perB > ws_size) chunk >>= 1;
    float* wsbuf = (float*)d_ws;

    for (int c0 = 0; c0 < BB; c0 += chunk) {
        const float* xc   = x + (size_t)c0 * 32 * TT;
        float*       outc = out + (size_t)c0 * TT * 22;
        const int nblk = (chunk * 2) / 4;  // 4 sequences (waves) per block

        reduce_x<<<dim3(2, chunk), 256, 0, stream>>>(xc, wsbuf);

        lstm_layer<1><<<nblk, 256, 0, stream>>>(wsbuf, outc, W_ih0, W_hh, b_ih, b_hh);

        for (int l = 1; l < NL; l++) {
            const float* src = (l & 1) ? outc : wsbuf;
            float*       dst = (l & 1) ? wsbuf : outc;
            lstm_layer<22><<<nblk, 256, 0, stream>>>(
                src, dst,
                W_ih_rest + (size_t)(l - 1) * 2 * GG * 22,
                W_hh + (size_t)l * 2 * GG * HH,
                b_ih + (size_t)l * 2 * GG,
                b_hh + (size_t)l * 2 * GG);
        }
    }
}